// Round 9
// baseline (543.993 us; speedup 1.0000x reference)
//
#include <hip/hip_runtime.h>

#define DIM 512
#define HEADS 8
#define HD 64
#define NB 8
#define NS 2048
#define SCALE_INV 0.125f
#define C2F 0.18033688011112042f   // SCALE_INV * log2(e): exp(s/8) = 2^(s*C2F)
#define NEG_BIG -1e30f
#define QSZ 8388608   // NB*HEADS*NS*HD = NB*NS*DIM

typedef __attribute__((ext_vector_type(8))) short bf16x8;
typedef __attribute__((ext_vector_type(4))) float f32x4;

__device__ __forceinline__ float elu_f(float x) {
    return x > 0.0f ? x : (__expf(x) - 1.0f);
}
__device__ __forceinline__ short f2bf(float x) {            // RNE
    union { float f; unsigned u; } v; v.f = x;
    unsigned r = v.u + 0x7FFFu + ((v.u >> 16) & 1u);
    return (short)(r >> 16);
}
__device__ __forceinline__ float exp2_hw(float x) {         // v_exp_f32 = 2^x
    float r; asm("v_exp_f32 %0, %1" : "=v"(r) : "v"(x)); return r;
}
__device__ __forceinline__ unsigned cvt_pk_bf16(float a, float b) {  // lo=a, hi=b, RNE
    unsigned r; asm("v_cvt_pk_bf16_f32 %0, %1, %2" : "=v"(r) : "v"(a), "v"(b)); return r;
}
// gfx950 cross-lane swaps (VALU pipe, not LDS):
// pl32: a' = [a.lo32 | b.lo32], b' = [a.hi32 | b.hi32]
// pl16: within each 32-half, a' = [a.evenq, b.evenq], b' = [a.oddq, b.oddq]
__device__ __forceinline__ void pl32_swap(unsigned &a, unsigned &b) {
    asm volatile("v_permlane32_swap_b32 %0, %1" : "+v"(a), "+v"(b));
}
__device__ __forceinline__ void pl16_swap(unsigned &a, unsigned &b) {
    asm volatile("v_permlane16_swap_b32 %0, %1" : "+v"(a), "+v"(b));
}

// async global->LDS. Dest is wave-uniform base + lane*size (linear); swizzles
// are applied by permuting the per-lane SOURCE chunk (m173 pattern).
__device__ __forceinline__ void gload16(const void* g, void* l) {
    __builtin_amdgcn_global_load_lds(
        (const __attribute__((address_space(1))) unsigned*)g,
        (__attribute__((address_space(3))) unsigned*)l, 16, 0, 0);
}
__device__ __forceinline__ void gload4(const void* g, void* l) {
    __builtin_amdgcn_global_load_lds(
        (const __attribute__((address_space(1))) unsigned*)g,
        (__attribute__((address_space(3))) unsigned*)l, 4, 0, 0);
}

// ---------------------------------------------------------------------------
// prep: x->bf16; Wqkv rows permuted n=h*192+d*3+w -> n'=w*512+h*64+d, ->bf16;
// Wout->bf16; bqkv permuted (fp32); mask -> float bias table.
// ---------------------------------------------------------------------------
#define X4 2097152            // x elems/4
#define W14 196608            // Wqkv elems/4
#define W24 65536             // Wout elems/4
__global__ __launch_bounds__(256) void prep(
    const float* __restrict__ x, const float* __restrict__ Wqkv,
    const float* __restrict__ bqkv, const float* __restrict__ Wout,
    const int* __restrict__ mask,
    short* __restrict__ xb, short* __restrict__ Wp,
    float* __restrict__ bp, short* __restrict__ Wob,
    float* __restrict__ maskf)
{
    int i = blockIdx.x * 256 + threadIdx.x;
    if (i < X4) {
        float4 v = *(const float4*)(x + (size_t)i * 4);
        ushort4 o; o.x = (unsigned short)f2bf(v.x); o.y = (unsigned short)f2bf(v.y);
        o.z = (unsigned short)f2bf(v.z); o.w = (unsigned short)f2bf(v.w);
        *(ushort4*)(xb + (size_t)i * 4) = o;
    } else if (i < X4 + W14) {
        int j = i - X4;
        int np = j >> 7, k = (j & 127) * 4;
        int w = np >> 9, h = (np >> 6) & 7, d = np & 63;
        int n = h * 192 + d * 3 + w;
        float4 v = *(const float4*)(Wqkv + (size_t)n * 512 + k);
        ushort4 o; o.x = (unsigned short)f2bf(v.x); o.y = (unsigned short)f2bf(v.y);
        o.z = (unsigned short)f2bf(v.z); o.w = (unsigned short)f2bf(v.w);
        *(ushort4*)(Wp + (size_t)np * 512 + k) = o;
    } else if (i < X4 + W14 + W24) {
        int j = i - X4 - W14;
        float4 v = *(const float4*)(Wout + (size_t)j * 4);
        ushort4 o; o.x = (unsigned short)f2bf(v.x); o.y = (unsigned short)f2bf(v.y);
        o.z = (unsigned short)f2bf(v.z); o.w = (unsigned short)f2bf(v.w);
        *(ushort4*)(Wob + (size_t)j * 4) = o;
    } else if (i < X4 + W14 + W24 + 1536) {
        int j = i - X4 - W14 - W24;   // 0..1535
        int w = j >> 9, h = (j >> 6) & 7, d = j & 63;
        bp[j] = bqkv[h * 192 + d * 3 + w];
    } else {
        int j = i - X4 - W14 - W24 - 1536;   // 0..16383
        maskf[j] = mask[j] ? NEG_BIG : 0.0f;
    }
}

// ---------------------------------------------------------------------------
// QKV GEMM, bf16 MFMA 16x16x32, 128x128 tile, BK=64, 256 threads (2x2 waves).
// 2-phase PIPELINED staging: LDS double-buffered (64KB); per step:
// sync(drain cur) -> issue next-step gload_lds into buf^1 -> compute cur.
// Epilogue: Q/K -> [b,h,s,d]; V -> ELU, transposed, TILE-MAJOR.
// ---------------------------------------------------------------------------
__global__ __launch_bounds__(256) void qkv_mfma(
    const short* __restrict__ A, const short* __restrict__ Bw,
    const float* __restrict__ bp, short* __restrict__ QKV)
{
    __shared__ short smem[4 * 128 * 64];     // [buf][A|B], 16KB each quarter
    const int t = threadIdx.x, lane = t & 63, wv = t >> 6;
    const int c = lane & 15, quad = lane >> 4;
    const int wr = wv >> 1, wc = wv & 1;
    const int rsub = lane >> 3;
    const int csA = (lane & 7) ^ rsub;       // source chunk for XOR dest swizzle
    const int m0 = blockIdx.x * 128, n0 = blockIdx.y * 128;
    f32x4 acc[4][4];
    #pragma unroll
    for (int mi = 0; mi < 4; ++mi)
        #pragma unroll
        for (int nj = 0; nj < 4; ++nj)
            #pragma unroll
            for (int i = 0; i < 4; ++i) acc[mi][nj][i] = 0.0f;

    // prologue: stage step 0 into buf 0
    #pragma unroll
    for (int p = 0; p < 4; ++p) {
        int r = p * 32 + wv * 8 + rsub;
        gload16(A  + (size_t)(m0 + r) * 512 + csA * 8, &smem[(p * 4 + wv) * 512]);
        gload16(Bw + (size_t)(n0 + r) * 512 + csA * 8, &smem[8192 + (p * 4 + wv) * 512]);
    }

    #pragma unroll 2
    for (int step = 0; step < 8; ++step) {
        const int cur = step & 1;
        __syncthreads();                     // drains buf[cur] loads; prev compute done
        if (step < 7) {
            int k0n = (step + 1) * 64;
            #pragma unroll
            for (int p = 0; p < 4; ++p) {
                int r = p * 32 + wv * 8 + rsub;
                gload16(A  + (size_t)(m0 + r) * 512 + k0n + csA * 8,
                        &smem[(cur ^ 1) * 16384 + (p * 4 + wv) * 512]);
                gload16(Bw + (size_t)(n0 + r) * 512 + k0n + csA * 8,
                        &smem[(cur ^ 1) * 16384 + 8192 + (p * 4 + wv) * 512]);
            }
        }
        const short* As = &smem[cur * 16384];
        const short* Bs = &smem[cur * 16384 + 8192];
        bf16x8 af[4][2], bfr[4][2];
        #pragma unroll
        for (int mi = 0; mi < 4; ++mi) {
            int ar = wr * 64 + mi * 16 + c;
            af[mi][0] = *(const bf16x8*)&As[ar * 64 + ((quad       ^ (ar & 7)) * 8)];
            af[mi][1] = *(const bf16x8*)&As[ar * 64 + (((4 + quad) ^ (ar & 7)) * 8)];
        }
        #pragma unroll
        for (int nj = 0; nj < 4; ++nj) {
            int br = wc * 64 + nj * 16 + c;
            bfr[nj][0] = *(const bf16x8*)&Bs[br * 64 + ((quad       ^ (br & 7)) * 8)];
            bfr[nj][1] = *(const bf16x8*)&Bs[br * 64 + (((4 + quad) ^ (br & 7)) * 8)];
        }
        __builtin_amdgcn_s_setprio(1);
        #pragma unroll
        for (int mi = 0; mi < 4; ++mi)
            #pragma unroll
            for (int nj = 0; nj < 4; ++nj) {
                acc[mi][nj] = __builtin_amdgcn_mfma_f32_16x16x32_bf16(af[mi][0], bfr[nj][0], acc[mi][nj], 0, 0, 0);
                acc[mi][nj] = __builtin_amdgcn_mfma_f32_16x16x32_bf16(af[mi][1], bfr[nj][1], acc[mi][nj], 0, 0, 0);
            }
        __builtin_amdgcn_s_setprio(0);
    }

    const int w  = n0 >> 9;
    const int b  = m0 >> 11;
    const int hh = ((n0 + wc * 64) >> 6) & 7;
    float bv[4];
    #pragma unroll
    for (int nj = 0; nj < 4; ++nj) bv[nj] = bp[n0 + wc * 64 + nj * 16 + c];

    if (w < 2) {
        short* out = QKV + (size_t)w * QSZ + (size_t)(b * 8 + hh) * NS * 64;
        #pragma unroll
        for (int mi = 0; mi < 4; ++mi)
            #pragma unroll
            for (int i = 0; i < 4; ++i) {
                int s = (m0 & (NS - 1)) + wr * 64 + mi * 16 + quad * 4 + i;
                #pragma unroll
                for (int nj = 0; nj < 4; ++nj)
                    out[(size_t)s * 64 + nj * 16 + c] = f2bf(acc[mi][nj][i] + bv[nj]);
            }
    } else {
        __syncthreads();
        short* T = smem;                     // first 32KB
        #pragma unroll
        for (int mi = 0; mi < 4; ++mi)
            #pragma unroll
            for (int i = 0; i < 4; ++i) {
                int ml = wr * 64 + mi * 16 + quad * 4 + i;
                int mb = ml >> 3, mr = ml & 7;
                #pragma unroll
                for (int nj = 0; nj < 4; ++nj) {
                    int nl = wc * 64 + nj * 16 + c;
                    T[nl * 128 + ((mb ^ (nl & 15)) * 8) + mr] =
                        f2bf(elu_f(acc[mi][nj][i] + bv[nj]));
                }
            }
        __syncthreads();
        short* Vt = QKV + (size_t)2 * QSZ;
        #pragma unroll
        for (int p = 0; p < 8; ++p) {
            int idx = p * 256 + t, row = idx >> 4, ch = idx & 15;
            uint4 v = *(const uint4*)&T[row * 128 + ((ch ^ (row & 15)) * 8)];
            int d = row & 63;
            int h2 = ((n0 + row) >> 6) & 7;
            int sg = (m0 & (NS - 1)) + ch * 8;      // global s of first elem
            int kt = sg >> 6, ks = sg & 63;
            *(uint4*)(Vt + (((size_t)(b * 8 + h2) * 32 + kt) * 64 + d) * 64 + ks) = v;
        }
    }
}

// ---------------------------------------------------------------------------
// Flash attention. R9: occupancy push. R8 removed P from LDS (in-register
// permlane transpose); that left Pt used only for Q staging. Now Q B-frags
// load DIRECTLY from global (one-time, per-lane aligned 16B: verified
// bq[nj][0/1] = Q[q0+wq*32+nj*16+c][quad*8 / 32+quad*8 ..+7]) and Pt is
// deleted: LDS 49.5 -> 33.5 KB, so 3-4 blocks/CU fit (was 2). Cross-block
// waves are unsynchronized -> their phases overlap across the three
// ~40-50%-loaded pipes (MFMA/VALU/LDS) that R8 showed are individually
// unsaturated. launch_bounds(512,6): VGPR cap 85 (measured 56 -- no spill),
// occupancy resolves to LDS/VGPR min at runtime.
// ---------------------------------------------------------------------------
__global__ __launch_bounds__(512, 6) void attn_mfma(
    const short* __restrict__ Qg, const short* __restrict__ Kg,
    const short* __restrict__ Vg, const float* __restrict__ maskf,
    short* __restrict__ O)
{
    __shared__ short Ks[2][64 * 64];     // XOR-swizzled [k][d], dbuf
    __shared__ short Vs[2][64 * 64];     // rotation-swizzled [d][k], dbuf
    __shared__ float msk[2][64];
    __shared__ float lw[128];            // cross-k-half l exchange

    const int t = threadIdx.x;
    const int lane = t & 63;
    const int wv = t >> 6;               // 0..7
    const int wq = wv & 3;               // q-group: rows [wq*32, +32)
    const int wk = wv >> 2;              // k-half:  keys [wk*32, +32)
    const int c = lane & 15;
    const int quad = lane >> 4;
    const int bid = blockIdx.x;
    const int qt = bid & 15;             // group-major: 16 consecutive bids/group
    const int h  = (bid >> 4) & 7;
    const int b  = bid >> 7;
    const int g  = b * 8 + h;
    const size_t base = (size_t)g * NS * HD;
    const int q0 = qt * 128;

    const int rsub = lane >> 3;                  // row-within-8 of this lane
    const int csA  = (lane & 7) ^ rsub;          // XOR swizzle source chunk
    const int csV  = ((lane & 7) - rsub) & 7;    // rotation swizzle source chunk

    // ---- prologue: issue K/V tile 0 + mask
    {
        int r = wv * 8 + rsub;
        gload16(Kg + base + (size_t)r * HD + csA * 8, &Ks[0][wv * 512]);
        gload16(Vg + (((size_t)g * 32 + 0) * 64 + r) * 64 + csV * 8, &Vs[0][wv * 512]);
        if (wv == 0) gload4(maskf + (size_t)b * NS + lane, &msk[0][0]);
    }
    // Q B-frags DIRECT from global (loop-invariant, per-lane 16B aligned)
    bf16x8 bq[2][2];
    {
        const short* q0p = Qg + base + (size_t)(q0 + wq * 32 + c) * HD + quad * 8;
        const short* q1p = Qg + base + (size_t)(q0 + wq * 32 + 16 + c) * HD + quad * 8;
        bq[0][0] = *(const bf16x8*)(q0p);
        bq[0][1] = *(const bf16x8*)(q0p + 32);
        bq[1][0] = *(const bf16x8*)(q1p);
        bq[1][1] = *(const bf16x8*)(q1p + 32);
    }
    __syncthreads();     // tile0 landed (implicit vmcnt(0) drain; Q regs too)

    // issue tile 1 (flies under compute(0))
    {
        int r = wv * 8 + rsub;
        gload16(Kg + base + (size_t)(64 + r) * HD + csA * 8, &Ks[1][wv * 512]);
        gload16(Vg + (((size_t)g * 32 + 1) * 64 + r) * 64 + csV * 8, &Vs[1][wv * 512]);
        if (wv == 0) gload4(maskf + (size_t)b * NS + 64 + lane, &msk[1][0]);
    }

    bf16x8 onesA;
    #pragma unroll
    for (int i = 0; i < 8; ++i) onesA[i] = (short)0x3F80;   // bf16 1.0

    f32x4 o[4][2];
    #pragma unroll
    for (int dc = 0; dc < 4; ++dc)
        #pragma unroll
        for (int nj = 0; nj < 2; ++nj)
            #pragma unroll
            for (int i = 0; i < 4; ++i) o[dc][nj][i] = 0.0f;
    f32x4 lacc[2];
    #pragma unroll
    for (int nj = 0; nj < 2; ++nj)
        #pragma unroll
        for (int i = 0; i < 4; ++i) lacc[nj][i] = 0.0f;

    const int kbase = wk * 32;                 // this wave's k-half

    for (int kt = 0; kt < 32; ++kt) {
        const int cur = kt & 1;
        const short* Kc = Ks[cur];
        const short* Vc = Vs[cur];

        // ---- S^T = K Q^T : 2 k-subtiles x 2 q-subtiles ----
        f32x4 st[2][2];
        __builtin_amdgcn_s_setprio(1);
        #pragma unroll
        for (int ks = 0; ks < 2; ++ks) {
            int kr = kbase + ks * 16 + c;
            bf16x8 ak0 = *(const bf16x8*)&Kc[kr * 64 + ((quad       ^ (kr & 7)) * 8)];
            bf16x8 ak1 = *(const bf16x8*)&Kc[kr * 64 + (((4 + quad) ^ (kr & 7)) * 8)];
            #pragma unroll
            for (int nj = 0; nj < 2; ++nj) {
                f32x4 a = {0.0f, 0.0f, 0.0f, 0.0f};
                a = __builtin_amdgcn_mfma_f32_16x16x32_bf16(ak0, bq[nj][0], a, 0, 0, 0);
                a = __builtin_amdgcn_mfma_f32_16x16x32_bf16(ak1, bq[nj][1], a, 0, 0, 0);
                st[ks][nj] = a;
            }
        }
        __builtin_amdgcn_s_setprio(0);

        // ---- softmax + in-register P quad-transpose (no LDS) ----
        // lane has p[k = ks*16 + quad*4 + i]; B-frag needs k = quad*8 + j.
        float4 mb0 = *(const float4*)&msk[cur][kbase + quad * 4];
        float4 mb1 = *(const float4*)&msk[cur][kbase + 16 + quad * 4];
        bf16x8 bpf[2];
        #pragma unroll
        for (int nj = 0; nj < 2; ++nj) {
            float p00 = exp2_hw(st[0][nj][0] * C2F + mb0.x);
            float p01 = exp2_hw(st[0][nj][1] * C2F + mb0.y);
            float p02 = exp2_hw(st[0][nj][2] * C2F + mb0.z);
            float p03 = exp2_hw(st[0][nj][3] * C2F + mb0.w);
            float p10 = exp2_hw(st[1][nj][0] * C2F + mb1.x);
            float p11 = exp2_hw(st[1][nj][1] * C2F + mb1.y);
            float p12 = exp2_hw(st[1][nj][2] * C2F + mb1.z);
            float p13 = exp2_hw(st[1][nj][3] * C2F + mb1.w);
            unsigned x0 = cvt_pk_bf16(p00, p01);   // ks0, k=quad*4+0,1
            unsigned x1 = cvt_pk_bf16(p02, p03);   // ks0, k=quad*4+2,3
            unsigned y0 = cvt_pk_bf16(p10, p11);   // ks1, k=16+quad*4+0,1
            unsigned y1 = cvt_pk_bf16(p12, p13);   // ks1, k=16+quad*4+2,3
            pl32_swap(x0, y0); pl16_swap(x0, y0);  // x0: k=8q+0,1  y0: k=8q+4,5
            pl32_swap(x1, y1); pl16_swap(x1, y1);  // x1: k=8q+2,3  y1: k=8q+6,7
            union { unsigned u[4]; bf16x8 v; } pw;
            pw.u[0] = x0; pw.u[1] = x1; pw.u[2] = y0; pw.u[3] = y1;
            bpf[nj] = pw.v;
        }

        __builtin_amdgcn_s_setprio(1);
        // l via MFMA: column sums of P (all output rows identical)
        #pragma unroll
        for (int nj = 0; nj < 2; ++nj)
            lacc[nj] = __builtin_amdgcn_mfma_f32_16x16x32_bf16(onesA, bpf[nj], lacc[nj], 0, 0, 0);
        // O^T += V^T P^T over this wave's k-half (K=32 contraction)
        #pragma unroll
        for (int dc = 0; dc < 4; ++dc) {
            int d = dc * 16 + c;
            int vrot = 8 * (d & 7);
            bf16x8 av = *(const bf16x8*)&Vc[d * 64 + ((kbase + quad * 8 + vrot) & 63)];
            #pragma unroll
            for (int nj = 0; nj < 2; ++nj)
                o[dc][nj] = __builtin_amdgcn_mfma_f32_16x16x32_bf16(av, bpf[nj], o[dc][nj], 0, 0, 0);
        }
        __builtin_amdgcn_s_setprio(0);

        // all waves done with buf[cur]; drain of tile kt+1's loads (in flight
        // during the compute above) happens in this barrier's implicit waitcnt
        __syncthreads();

        if (kt + 2 < 32) {
            int r = wv * 8 + rsub;
            int k0n = (kt + 2) * 64;
            gload16(Kg + base + (size_t)(k0n + r) * HD + csA * 8, &Ks[cur][wv * 512]);
            gload16(Vg + (((size_t)g * 32 + (kt + 2)) * 64 + r) * 64 + csV * 8, &Vs[cur][wv * 512]);
            if (wv == 0) gload4(maskf + (size_t)b * NS + k0n + lane, &msk[cur][0]);
        }
    }

    // ---- cross-k-half reduction through dead Ks/Vs (32KB = 4 waves x 8KB) ----
    float* rb = ((wq < 2) ? (float*)&Ks[0][0] : (float*)&Vs[0][0])
                + (wq & 1) * 2048 + lane * 32;
    if (wk == 1) {
        #pragma unroll
        for (int dc = 0; dc < 4; ++dc)
            #pragma unroll
            for (int nj = 0; nj < 2; ++nj)
                *(f32x4*)&rb[(((dc << 1) | nj) ^ (lane & 7)) << 2] = o[dc][nj];
        if (quad == 0) {
            lw[wq * 32 + c]      = lacc[0][0];
            lw[wq * 32 + 16 + c] = lacc[1][0];
        }
    }
    __syncthreads();
    if (wk == 0) {
        float l0 = lacc[0][0] + lw[wq * 32 + c];
        float l1 = lacc[1][0] + lw[wq * 32 + 16 + c];
        float inv0 = 1.0f / l0;                 // key 0 always unmasked
        float inv1 = 1.0f / l1;
        #pragma unroll
        for (int dc = 0; dc < 4; ++dc)
            #pragma unroll
            for (int nj = 0; nj < 2; ++nj)
                o[dc][nj] += *(const f32x4*)&rb[(((dc << 1) | nj) ^ (lane & 7)) << 2];
        #pragma unroll
        for (int nj = 0; nj < 2; ++nj) {
            float inv = nj ? inv1 : inv0;
            int q = q0 + wq * 32 + nj * 16 + c;
            short* orow = O + ((size_t)(b * NS + q)) * DIM + h * HD + quad * 4;
            #pragma unroll
            for (int dc = 0; dc < 4; ++dc) {
                uint2 pk;
                pk.x = (unsigned)(unsigned short)f2bf(o[dc][nj][0] * inv)
                     | ((unsigned)(unsigned short)f2bf(o[dc][nj][1] * inv) << 16);
                pk.y = (unsigned)(unsigned short)f2bf(o[dc][nj][2] * inv)
                     | ((unsigned)(unsigned short)f2bf(o[dc][nj][3] * inv) << 16);
                *(uint2*)(orow + dc * 16) = pk;
            }
        }
    }
}

// ---------------------------------------------------------------------------
// FUSED out-projection + LayerNorm + ELU, 2-phase PIPELINED staging.
// Z = ATT @ Wout^T + bout, row-wise LN+ELU from live accumulators -> out.
// Block: 64 rows x FULL 512 cols; 512 thr = 8 waves (2 m x 4 n), acc[2][8].
// LDS: As 2x8KB + Bs 2x64KB = 144KB (1 block/CU; latency hidden by pipeline).
// Row stats: shfl_xor butterfly over 16 c-lanes -> cross-wave via dead As.
// ---------------------------------------------------------------------------
__global__ __launch_bounds__(512) void out_ln(
    const short* __restrict__ A, const short* __restrict__ Bw,
    const float* __restrict__ bias, const float* __restrict__ g,
    const float* __restrict__ bt, float* __restrict__ out)
{
    __shared__ short As[2][64 * 64];
    __shared__ short Bs[2][512 * 64];
    const int t = threadIdx.x, lane = t & 63, wv = t >> 6;
    const int c = lane & 15, quad = lane >> 4;
    const int wr = wv >> 2, wc = wv & 3;          // 2 x 4 wave grid
    const int rsub = lane >> 3;
    const int csA = (lane & 7) ^ rsub;
    const int m0 = blockIdx.x * 64;

    float bv[8], gg[8], bb[8];
    #pragma unroll
    for (int nj = 0; nj < 8; ++nj) {
        int col = wc * 128 + nj * 16 + c;
        bv[nj] = bias[col]; gg[nj] = g[col]; bb[nj] = bt[col];
    }

    f32x4 acc[2][8];
    #pragma unroll
    for (int mi = 0; mi < 2; ++mi)
        #pragma unroll
        for (int nj = 0; nj < 8; ++nj)
            #pragma unroll
            for (int i = 0; i < 4; ++i) acc[mi][nj][i] = 0.0f;

    // prologue: stage step 0 into buf 0
    gload16(A + (size_t)(m0 + wv * 8 + rsub) * 512 + csA * 8, &As[0][wv * 512]);
    #pragma unroll
    for (int p = 0; p < 8; ++p) {
        int r = p * 64 + wv * 8 + rsub;
        gload16(Bw + (size_t)r * 512 + csA * 8, &Bs[0][(p * 8 + wv) * 512]);
    }

    #pragma unroll 2
    for (int step = 0; step < 8; ++step) {
        const int cur = step & 1;
        __syncthreads();                     // drains buf[cur] loads
        if (step < 7) {
            int k0n = (step + 1) * 64;
            gload16(A + (size_t)(m0 + wv * 8 + rsub) * 512 + k0n + csA * 8,
                    &As[cur ^ 1][wv * 512]);
            #pragma unroll
            for (int p = 0; p < 8; ++p) {
                int r = p * 64 + wv * 8 + rsub;
                gload16(Bw + (size_t)r * 512 + k0n + csA * 8,
                        &Bs[cur ^ 1][(p * 8 + wv) * 512]);
            }
        }
        bf16x8 af[2][2];
        #pragma unroll
        for (int mi = 0; mi < 2; ++mi) {
            int ar = wr * 32 + mi * 16 + c;
            af[mi][0] = *(const bf16x8*)&As[cur][ar * 64 + ((quad       ^ (ar & 7)) * 8)];
            af[mi][1] = *(const bf16x8*)&As[cur][ar * 64 + (((4 + quad) ^ (ar & 7)) * 8)];
        }
        __builtin_amdgcn_s_setprio(1);
        #pragma unroll
        for (int nj = 0; nj < 8; ++nj) {
            int br = wc * 128 + nj * 16 + c;
            bf16x8 b0 = *(const bf16x8*)&Bs[cur][br * 64 + ((quad       ^ (br & 7)) * 8)];
            bf16x8 b1 = *(const bf16x8*)&Bs[cur][br * 64 + (((4 + quad) ^ (br & 7)) * 8)];
            #pragma unroll
            for (int mi = 0; mi < 2; ++mi) {
                acc[mi][nj] = __builtin_amdgcn_mfma_f32_16x16x32_bf16(af[mi][0], b0, acc[mi][nj], 0, 0, 0);
                acc[mi][nj] = __builtin_amdgcn_mfma_f32_16x16x32_bf16(af[mi][1], b1, acc[mi][nj], 0, 0, 0);
            }
        }
        __builtin_amdgcn_s_setprio(0);
    }
    __syncthreads();                       // all frag reads done; As reusable

    float* red = (float*)&As[0][0];        // s: [4 wc][64 row], ss at +256
    #pragma unroll
    for (int mi = 0; mi < 2; ++mi)
        #pragma unroll
        for (int i = 0; i < 4; ++i) {
            float s = 0.0f, ss = 0.0f;
            #pragma unroll
            for (int nj = 0; nj < 8; ++nj) {
                float z = acc[mi][nj][i] + bv[nj];
                s += z; ss += z * z;
            }
            s  += __shfl_xor(s, 1);  s  += __shfl_xor(s, 2);
            s  += __shfl_xor(s, 4);  s  += __shfl_xor(s, 8);
            ss += __shfl_xor(ss, 1); ss += __shfl_xor(ss, 2);
            ss += __shfl_xor(ss, 4); ss += __shfl_xor(ss, 8);
            if (c == 0) {
                int row = wr * 32 + mi * 16 + quad * 4 + i;
                red[wc * 64 + row]       = s;
                red[256 + wc * 64 + row] = ss;
            }
        }
    __syncthreads();
    #pragma unroll
    for (int mi = 0; mi < 2; ++mi)
        #pragma unroll
        for (int i = 0; i < 4; ++i) {
            int row = wr * 32 + mi * 16 + quad * 4 + i;
            float S1 = red[row] + red[64 + row] + red[128 + row] + red[192 + row];
            float S2 = red[256 + row] + red[320 + row] + red[384 + row] + red[448 + row];
            float mu   = S1 * (1.0f / DIM);
            float var  = S2 * (1.0f / DIM) - mu * mu;
            float rstd = rsqrtf(var + 1e-5f);
            float* orow = out + (size_t)(m0 + row) * DIM + wc * 128 + c;
            #pragma unroll
            for (int nj = 0; nj < 8; ++nj) {
                float z = acc[mi][nj][i] + bv[nj];
                orow[nj * 16] = elu_f((z - mu) * rstd * gg[nj] + bb[nj]);
            }
        }
}

extern "C" void kernel_launch(void* const* d_in, const int* in_sizes, int n_in,
                              void* d_out, int out_size, void* d_ws, size_t ws_size,
                              hipStream_t stream)
{
    const float* x    = (const float*)d_in[0];
    const int*   mask = (const int*)d_in[1];
    const float* Wqkv = (const float*)d_in[2];
    const float* bqkv = (const float*)d_in[3];
    const float* Wout = (const float*)d_in[4];
    const float* bout = (const float*)d_in[5];
    const float* ln_g = (const float*)d_in[6];
    const float* ln_b = (const float*)d_in[7];
    float* out = (float*)d_out;

    short* xb   = (short*)d_ws;           // QSZ
    short* Wp   = xb + QSZ;               // 786432
    short* Wob  = Wp + 786432;            // 262144
    short* QKV  = Wob + 262144;           // 3*QSZ  (Q | K | Vt)
    short* ATTb = QKV + 3 * (size_t)QSZ;  // QSZ
    float* bp   = (float*)(ATTb + QSZ);   // 1536
    float* Zb   = bp + 1536;              // region kept for maskf placement
    float* maskf = Zb + (size_t)QSZ - 16384;

    prep<<<9286, 256, 0, stream>>>(x, Wqkv, bqkv, Wout, mask, xb, Wp, bp, Wob, maskf);
    qkv_mfma<<<dim3(128, 12), 256, 0, stream>>>(xb, Wp, bp, QKV);
    attn_mfma<<<1024, 512, 0, stream>>>(QKV, QKV + QSZ, QKV + 2 * (size_t)QSZ, maskf, ATTb);
    out_ln<<<256, 512, 0, stream>>>(ATTb, Wob, bout, ln_g, ln_b, out);
}

// Round 10
// 232.550 us; speedup vs baseline: 2.3393x; 2.3393x over previous
//
#include <hip/hip_runtime.h>

#define DIM 512
#define HEADS 8
#define HD 64
#define NB 8
#define NS 2048
#define SCALE_INV 0.125f
#define C2F 0.18033688011112042f   // SCALE_INV * log2(e): exp(s/8) = 2^(s*C2F)
#define NEG_BIG -1e30f
#define QSZ 8388608   // NB*HEADS*NS*HD = NB*NS*DIM

typedef __attribute__((ext_vector_type(8))) short bf16x8;
typedef __attribute__((ext_vector_type(4))) float f32x4;

__device__ __forceinline__ float elu_f(float x) {
    return x > 0.0f ? x : (__expf(x) - 1.0f);
}
__device__ __forceinline__ short f2bf(float x) {            // RNE
    union { float f; unsigned u; } v; v.f = x;
    unsigned r = v.u + 0x7FFFu + ((v.u >> 16) & 1u);
    return (short)(r >> 16);
}
__device__ __forceinline__ float exp2_hw(float x) {         // v_exp_f32 = 2^x
    float r; asm("v_exp_f32 %0, %1" : "=v"(r) : "v"(x)); return r;
}
__device__ __forceinline__ unsigned cvt_pk_bf16(float a, float b) {  // lo=a, hi=b, RNE
    unsigned r; asm("v_cvt_pk_bf16_f32 %0, %1, %2" : "=v"(r) : "v"(a), "v"(b)); return r;
}
// gfx950 cross-lane swaps (VALU pipe, not LDS):
// pl32: a' = [a.lo32 | b.lo32], b' = [a.hi32 | b.hi32]
// pl16: within each 32-half, a' = [a.evenq, b.evenq], b' = [a.oddq, b.oddq]
__device__ __forceinline__ void pl32_swap(unsigned &a, unsigned &b) {
    asm volatile("v_permlane32_swap_b32 %0, %1" : "+v"(a), "+v"(b));
}
__device__ __forceinline__ void pl16_swap(unsigned &a, unsigned &b) {
    asm volatile("v_permlane16_swap_b32 %0, %1" : "+v"(a), "+v"(b));
}

// async global->LDS. Dest is wave-uniform base + lane*size (linear); swizzles
// are applied by permuting the per-lane SOURCE chunk (m173 pattern).
__device__ __forceinline__ void gload16(const void* g, void* l) {
    __builtin_amdgcn_global_load_lds(
        (const __attribute__((address_space(1))) unsigned*)g,
        (__attribute__((address_space(3))) unsigned*)l, 16, 0, 0);
}
__device__ __forceinline__ void gload4(const void* g, void* l) {
    __builtin_amdgcn_global_load_lds(
        (const __attribute__((address_space(1))) unsigned*)g,
        (__attribute__((address_space(3))) unsigned*)l, 4, 0, 0);
}

// ---------------------------------------------------------------------------
// prep: x->bf16; Wqkv rows permuted n=h*192+d*3+w -> n'=w*512+h*64+d, ->bf16;
// Wout->bf16; bqkv permuted (fp32); mask -> float bias table.
// ---------------------------------------------------------------------------
#define X4 2097152            // x elems/4
#define W14 196608            // Wqkv elems/4
#define W24 65536             // Wout elems/4
__global__ __launch_bounds__(256) void prep(
    const float* __restrict__ x, const float* __restrict__ Wqkv,
    const float* __restrict__ bqkv, const float* __restrict__ Wout,
    const int* __restrict__ mask,
    short* __restrict__ xb, short* __restrict__ Wp,
    float* __restrict__ bp, short* __restrict__ Wob,
    float* __restrict__ maskf)
{
    int i = blockIdx.x * 256 + threadIdx.x;
    if (i < X4) {
        float4 v = *(const float4*)(x + (size_t)i * 4);
        ushort4 o; o.x = (unsigned short)f2bf(v.x); o.y = (unsigned short)f2bf(v.y);
        o.z = (unsigned short)f2bf(v.z); o.w = (unsigned short)f2bf(v.w);
        *(ushort4*)(xb + (size_t)i * 4) = o;
    } else if (i < X4 + W14) {
        int j = i - X4;
        int np = j >> 7, k = (j & 127) * 4;
        int w = np >> 9, h = (np >> 6) & 7, d = np & 63;
        int n = h * 192 + d * 3 + w;
        float4 v = *(const float4*)(Wqkv + (size_t)n * 512 + k);
        ushort4 o; o.x = (unsigned short)f2bf(v.x); o.y = (unsigned short)f2bf(v.y);
        o.z = (unsigned short)f2bf(v.z); o.w = (unsigned short)f2bf(v.w);
        *(ushort4*)(Wp + (size_t)np * 512 + k) = o;
    } else if (i < X4 + W14 + W24) {
        int j = i - X4 - W14;
        float4 v = *(const float4*)(Wout + (size_t)j * 4);
        ushort4 o; o.x = (unsigned short)f2bf(v.x); o.y = (unsigned short)f2bf(v.y);
        o.z = (unsigned short)f2bf(v.z); o.w = (unsigned short)f2bf(v.w);
        *(ushort4*)(Wob + (size_t)j * 4) = o;
    } else if (i < X4 + W14 + W24 + 1536) {
        int j = i - X4 - W14 - W24;   // 0..1535
        int w = j >> 9, h = (j >> 6) & 7, d = j & 63;
        bp[j] = bqkv[h * 192 + d * 3 + w];
    } else {
        int j = i - X4 - W14 - W24 - 1536;   // 0..16383
        maskf[j] = mask[j] ? NEG_BIG : 0.0f;
    }
}

// ---------------------------------------------------------------------------
// QKV GEMM, bf16 MFMA 16x16x32, 128x128 tile, BK=64, 256 threads (2x2 waves).
// 2-phase PIPELINED staging: LDS double-buffered (64KB); per step:
// sync(drain cur) -> issue next-step gload_lds into buf^1 -> compute cur.
// Epilogue: Q/K -> [b,h,s,d]; V -> ELU, transposed, TILE-MAJOR.
// ---------------------------------------------------------------------------
__global__ __launch_bounds__(256) void qkv_mfma(
    const short* __restrict__ A, const short* __restrict__ Bw,
    const float* __restrict__ bp, short* __restrict__ QKV)
{
    __shared__ short smem[4 * 128 * 64];     // [buf][A|B], 16KB each quarter
    const int t = threadIdx.x, lane = t & 63, wv = t >> 6;
    const int c = lane & 15, quad = lane >> 4;
    const int wr = wv >> 1, wc = wv & 1;
    const int rsub = lane >> 3;
    const int csA = (lane & 7) ^ rsub;       // source chunk for XOR dest swizzle
    const int m0 = blockIdx.x * 128, n0 = blockIdx.y * 128;
    f32x4 acc[4][4];
    #pragma unroll
    for (int mi = 0; mi < 4; ++mi)
        #pragma unroll
        for (int nj = 0; nj < 4; ++nj)
            #pragma unroll
            for (int i = 0; i < 4; ++i) acc[mi][nj][i] = 0.0f;

    // prologue: stage step 0 into buf 0
    #pragma unroll
    for (int p = 0; p < 4; ++p) {
        int r = p * 32 + wv * 8 + rsub;
        gload16(A  + (size_t)(m0 + r) * 512 + csA * 8, &smem[(p * 4 + wv) * 512]);
        gload16(Bw + (size_t)(n0 + r) * 512 + csA * 8, &smem[8192 + (p * 4 + wv) * 512]);
    }

    #pragma unroll 2
    for (int step = 0; step < 8; ++step) {
        const int cur = step & 1;
        __syncthreads();                     // drains buf[cur] loads; prev compute done
        if (step < 7) {
            int k0n = (step + 1) * 64;
            #pragma unroll
            for (int p = 0; p < 4; ++p) {
                int r = p * 32 + wv * 8 + rsub;
                gload16(A  + (size_t)(m0 + r) * 512 + k0n + csA * 8,
                        &smem[(cur ^ 1) * 16384 + (p * 4 + wv) * 512]);
                gload16(Bw + (size_t)(n0 + r) * 512 + k0n + csA * 8,
                        &smem[(cur ^ 1) * 16384 + 8192 + (p * 4 + wv) * 512]);
            }
        }
        const short* As = &smem[cur * 16384];
        const short* Bs = &smem[cur * 16384 + 8192];
        bf16x8 af[4][2], bfr[4][2];
        #pragma unroll
        for (int mi = 0; mi < 4; ++mi) {
            int ar = wr * 64 + mi * 16 + c;
            af[mi][0] = *(const bf16x8*)&As[ar * 64 + ((quad       ^ (ar & 7)) * 8)];
            af[mi][1] = *(const bf16x8*)&As[ar * 64 + (((4 + quad) ^ (ar & 7)) * 8)];
        }
        #pragma unroll
        for (int nj = 0; nj < 4; ++nj) {
            int br = wc * 64 + nj * 16 + c;
            bfr[nj][0] = *(const bf16x8*)&Bs[br * 64 + ((quad       ^ (br & 7)) * 8)];
            bfr[nj][1] = *(const bf16x8*)&Bs[br * 64 + (((4 + quad) ^ (br & 7)) * 8)];
        }
        __builtin_amdgcn_s_setprio(1);
        #pragma unroll
        for (int mi = 0; mi < 4; ++mi)
            #pragma unroll
            for (int nj = 0; nj < 4; ++nj) {
                acc[mi][nj] = __builtin_amdgcn_mfma_f32_16x16x32_bf16(af[mi][0], bfr[nj][0], acc[mi][nj], 0, 0, 0);
                acc[mi][nj] = __builtin_amdgcn_mfma_f32_16x16x32_bf16(af[mi][1], bfr[nj][1], acc[mi][nj], 0, 0, 0);
            }
        __builtin_amdgcn_s_setprio(0);
    }

    const int w  = n0 >> 9;
    const int b  = m0 >> 11;
    const int hh = ((n0 + wc * 64) >> 6) & 7;
    float bv[4];
    #pragma unroll
    for (int nj = 0; nj < 4; ++nj) bv[nj] = bp[n0 + wc * 64 + nj * 16 + c];

    if (w < 2) {
        short* out = QKV + (size_t)w * QSZ + (size_t)(b * 8 + hh) * NS * 64;
        #pragma unroll
        for (int mi = 0; mi < 4; ++mi)
            #pragma unroll
            for (int i = 0; i < 4; ++i) {
                int s = (m0 & (NS - 1)) + wr * 64 + mi * 16 + quad * 4 + i;
                #pragma unroll
                for (int nj = 0; nj < 4; ++nj)
                    out[(size_t)s * 64 + nj * 16 + c] = f2bf(acc[mi][nj][i] + bv[nj]);
            }
    } else {
        __syncthreads();
        short* T = smem;                     // first 32KB
        #pragma unroll
        for (int mi = 0; mi < 4; ++mi)
            #pragma unroll
            for (int i = 0; i < 4; ++i) {
                int ml = wr * 64 + mi * 16 + quad * 4 + i;
                int mb = ml >> 3, mr = ml & 7;
                #pragma unroll
                for (int nj = 0; nj < 4; ++nj) {
                    int nl = wc * 64 + nj * 16 + c;
                    T[nl * 128 + ((mb ^ (nl & 15)) * 8) + mr] =
                        f2bf(elu_f(acc[mi][nj][i] + bv[nj]));
                }
            }
        __syncthreads();
        short* Vt = QKV + (size_t)2 * QSZ;
        #pragma unroll
        for (int p = 0; p < 8; ++p) {
            int idx = p * 256 + t, row = idx >> 4, ch = idx & 15;
            uint4 v = *(const uint4*)&T[row * 128 + ((ch ^ (row & 15)) * 8)];
            int d = row & 63;
            int h2 = ((n0 + row) >> 6) & 7;
            int sg = (m0 & (NS - 1)) + ch * 8;      // global s of first elem
            int kt = sg >> 6, ks = sg & 63;
            *(uint4*)(Vt + (((size_t)(b * 8 + h2) * 32 + kt) * 64 + d) * 64 + ks) = v;
        }
    }
}

// ---------------------------------------------------------------------------
// Flash attention. R10 = R9 structure with the proven (512,4) bounds.
// R9's (512,6) clamp (budget ~85) forced VGPR 40 + scratch spill
// (WRITE_SIZE 16MB->303MB, 4x dur) -- identical failure mode to R3.
// Rule: never tighten min-waves while adding live register state.
// Structure: P in-register (permlane transpose, R8); Q B-frags direct
// from global (one-time); Pt deleted -> LDS 33.5KB -> 3-4 blocks/CU.
// ---------------------------------------------------------------------------
__global__ __launch_bounds__(512, 4) void attn_mfma(
    const short* __restrict__ Qg, const short* __restrict__ Kg,
    const short* __restrict__ Vg, const float* __restrict__ maskf,
    short* __restrict__ O)
{
    __shared__ short Ks[2][64 * 64];     // XOR-swizzled [k][d], dbuf
    __shared__ short Vs[2][64 * 64];     // rotation-swizzled [d][k], dbuf
    __shared__ float msk[2][64];
    __shared__ float lw[128];            // cross-k-half l exchange

    const int t = threadIdx.x;
    const int lane = t & 63;
    const int wv = t >> 6;               // 0..7
    const int wq = wv & 3;               // q-group: rows [wq*32, +32)
    const int wk = wv >> 2;              // k-half:  keys [wk*32, +32)
    const int c = lane & 15;
    const int quad = lane >> 4;
    const int bid = blockIdx.x;
    const int qt = bid & 15;             // group-major: 16 consecutive bids/group
    const int h  = (bid >> 4) & 7;
    const int b  = bid >> 7;
    const int g  = b * 8 + h;
    const size_t base = (size_t)g * NS * HD;
    const int q0 = qt * 128;

    const int rsub = lane >> 3;                  // row-within-8 of this lane
    const int csA  = (lane & 7) ^ rsub;          // XOR swizzle source chunk
    const int csV  = ((lane & 7) - rsub) & 7;    // rotation swizzle source chunk

    // ---- prologue: issue K/V tile 0 + mask
    {
        int r = wv * 8 + rsub;
        gload16(Kg + base + (size_t)r * HD + csA * 8, &Ks[0][wv * 512]);
        gload16(Vg + (((size_t)g * 32 + 0) * 64 + r) * 64 + csV * 8, &Vs[0][wv * 512]);
        if (wv == 0) gload4(maskf + (size_t)b * NS + lane, &msk[0][0]);
    }
    // Q B-frags DIRECT from global (loop-invariant, per-lane 16B aligned)
    bf16x8 bq[2][2];
    {
        const short* q0p = Qg + base + (size_t)(q0 + wq * 32 + c) * HD + quad * 8;
        const short* q1p = Qg + base + (size_t)(q0 + wq * 32 + 16 + c) * HD + quad * 8;
        bq[0][0] = *(const bf16x8*)(q0p);
        bq[0][1] = *(const bf16x8*)(q0p + 32);
        bq[1][0] = *(const bf16x8*)(q1p);
        bq[1][1] = *(const bf16x8*)(q1p + 32);
    }
    __syncthreads();     // tile0 landed (implicit vmcnt(0) drain; Q regs too)

    // issue tile 1 (flies under compute(0))
    {
        int r = wv * 8 + rsub;
        gload16(Kg + base + (size_t)(64 + r) * HD + csA * 8, &Ks[1][wv * 512]);
        gload16(Vg + (((size_t)g * 32 + 1) * 64 + r) * 64 + csV * 8, &Vs[1][wv * 512]);
        if (wv == 0) gload4(maskf + (size_t)b * NS + 64 + lane, &msk[1][0]);
    }

    bf16x8 onesA;
    #pragma unroll
    for (int i = 0; i < 8; ++i) onesA[i] = (short)0x3F80;   // bf16 1.0

    f32x4 o[4][2];
    #pragma unroll
    for (int dc = 0; dc < 4; ++dc)
        #pragma unroll
        for (int nj = 0; nj < 2; ++nj)
            #pragma unroll
            for (int i = 0; i < 4; ++i) o[dc][nj][i] = 0.0f;
    f32x4 lacc[2];
    #pragma unroll
    for (int nj = 0; nj < 2; ++nj)
        #pragma unroll
        for (int i = 0; i < 4; ++i) lacc[nj][i] = 0.0f;

    const int kbase = wk * 32;                 // this wave's k-half

    for (int kt = 0; kt < 32; ++kt) {
        const int cur = kt & 1;
        const short* Kc = Ks[cur];
        const short* Vc = Vs[cur];

        // ---- S^T = K Q^T : 2 k-subtiles x 2 q-subtiles ----
        f32x4 st[2][2];
        __builtin_amdgcn_s_setprio(1);
        #pragma unroll
        for (int ks = 0; ks < 2; ++ks) {
            int kr = kbase + ks * 16 + c;
            bf16x8 ak0 = *(const bf16x8*)&Kc[kr * 64 + ((quad       ^ (kr & 7)) * 8)];
            bf16x8 ak1 = *(const bf16x8*)&Kc[kr * 64 + (((4 + quad) ^ (kr & 7)) * 8)];
            #pragma unroll
            for (int nj = 0; nj < 2; ++nj) {
                f32x4 a = {0.0f, 0.0f, 0.0f, 0.0f};
                a = __builtin_amdgcn_mfma_f32_16x16x32_bf16(ak0, bq[nj][0], a, 0, 0, 0);
                a = __builtin_amdgcn_mfma_f32_16x16x32_bf16(ak1, bq[nj][1], a, 0, 0, 0);
                st[ks][nj] = a;
            }
        }
        __builtin_amdgcn_s_setprio(0);

        // ---- softmax + in-register P quad-transpose (no LDS) ----
        // lane has p[k = ks*16 + quad*4 + i]; B-frag needs k = quad*8 + j.
        float4 mb0 = *(const float4*)&msk[cur][kbase + quad * 4];
        float4 mb1 = *(const float4*)&msk[cur][kbase + 16 + quad * 4];
        bf16x8 bpf[2];
        #pragma unroll
        for (int nj = 0; nj < 2; ++nj) {
            float p00 = exp2_hw(st[0][nj][0] * C2F + mb0.x);
            float p01 = exp2_hw(st[0][nj][1] * C2F + mb0.y);
            float p02 = exp2_hw(st[0][nj][2] * C2F + mb0.z);
            float p03 = exp2_hw(st[0][nj][3] * C2F + mb0.w);
            float p10 = exp2_hw(st[1][nj][0] * C2F + mb1.x);
            float p11 = exp2_hw(st[1][nj][1] * C2F + mb1.y);
            float p12 = exp2_hw(st[1][nj][2] * C2F + mb1.z);
            float p13 = exp2_hw(st[1][nj][3] * C2F + mb1.w);
            unsigned x0 = cvt_pk_bf16(p00, p01);   // ks0, k=quad*4+0,1
            unsigned x1 = cvt_pk_bf16(p02, p03);   // ks0, k=quad*4+2,3
            unsigned y0 = cvt_pk_bf16(p10, p11);   // ks1, k=16+quad*4+0,1
            unsigned y1 = cvt_pk_bf16(p12, p13);   // ks1, k=16+quad*4+2,3
            pl32_swap(x0, y0); pl16_swap(x0, y0);  // x0: k=8q+0,1  y0: k=8q+4,5
            pl32_swap(x1, y1); pl16_swap(x1, y1);  // x1: k=8q+2,3  y1: k=8q+6,7
            union { unsigned u[4]; bf16x8 v; } pw;
            pw.u[0] = x0; pw.u[1] = x1; pw.u[2] = y0; pw.u[3] = y1;
            bpf[nj] = pw.v;
        }

        __builtin_amdgcn_s_setprio(1);
        // l via MFMA: column sums of P (all output rows identical)
        #pragma unroll
        for (int nj = 0; nj < 2; ++nj)
            lacc[nj] = __builtin_amdgcn_mfma_f32_16x16x32_bf16(onesA, bpf[nj], lacc[nj], 0, 0, 0);
        // O^T += V^T P^T over this wave's k-half (K=32 contraction)
        #pragma unroll
        for (int dc = 0; dc < 4; ++dc) {
            int d = dc * 16 + c;
            int vrot = 8 * (d & 7);
            bf16x8 av = *(const bf16x8*)&Vc[d * 64 + ((kbase + quad * 8 + vrot) & 63)];
            #pragma unroll
            for (int nj = 0; nj < 2; ++nj)
                o[dc][nj] = __builtin_amdgcn_mfma_f32_16x16x32_bf16(av, bpf[nj], o[dc][nj], 0, 0, 0);
        }
        __builtin_amdgcn_s_setprio(0);

        // all waves done with buf[cur]; drain of tile kt+1's loads (in flight
        // during the compute above) happens in this barrier's implicit waitcnt
        __syncthreads();

        if (kt + 2 < 32) {
            int r = wv * 8 + rsub;
            int k0n = (kt + 2) * 64;
            gload16(Kg + base + (size_t)(k0n + r) * HD + csA * 8, &Ks[cur][wv * 512]);
            gload16(Vg + (((size_t)g * 32 + (kt + 2)) * 64 + r) * 64 + csV * 8, &Vs[cur][wv * 512]);
            if (wv == 0) gload4(maskf + (size_t)b * NS + k0n + lane, &msk[cur][0]);
        }
    }

    // ---- cross-k-half reduction through dead Ks/Vs (32KB = 4 waves x 8KB) ----
    float* rb = ((wq < 2) ? (float*)&Ks[0][0] : (float*)&Vs[0][0])
                + (wq & 1) * 2048 + lane * 32;
    if (wk == 1) {
        #pragma unroll
        for (int dc = 0; dc < 4; ++dc)
            #pragma unroll
            for (int nj = 0; nj < 2; ++nj)
                *(f32x4*)&rb[(((dc << 1) | nj) ^ (lane & 7)) << 2] = o[dc][nj];
        if (quad == 0) {
            lw[wq * 32 + c]      = lacc[0][0];
            lw[wq * 32 + 16 + c] = lacc[1][0];
        }
    }
    __syncthreads();
    if (wk == 0) {
        float l0 = lacc[0][0] + lw[wq * 32 + c];
        float l1 = lacc[1][0] + lw[wq * 32 + 16 + c];
        float inv0 = 1.0f / l0;                 // key 0 always unmasked
        float inv1 = 1.0f / l1;
        #pragma unroll
        for (int dc = 0; dc < 4; ++dc)
            #pragma unroll
            for (int nj = 0; nj < 2; ++nj)
                o[dc][nj] += *(const f32x4*)&rb[(((dc << 1) | nj) ^ (lane & 7)) << 2];
        #pragma unroll
        for (int nj = 0; nj < 2; ++nj) {
            float inv = nj ? inv1 : inv0;
            int q = q0 + wq * 32 + nj * 16 + c;
            short* orow = O + ((size_t)(b * NS + q)) * DIM + h * HD + quad * 4;
            #pragma unroll
            for (int dc = 0; dc < 4; ++dc) {
                uint2 pk;
                pk.x = (unsigned)(unsigned short)f2bf(o[dc][nj][0] * inv)
                     | ((unsigned)(unsigned short)f2bf(o[dc][nj][1] * inv) << 16);
                pk.y = (unsigned)(unsigned short)f2bf(o[dc][nj][2] * inv)
                     | ((unsigned)(unsigned short)f2bf(o[dc][nj][3] * inv) << 16);
                *(uint2*)(orow + dc * 16) = pk;
            }
        }
    }
}

// ---------------------------------------------------------------------------
// FUSED out-projection + LayerNorm + ELU, 2-phase PIPELINED staging.
// Z = ATT @ Wout^T + bout, row-wise LN+ELU from live accumulators -> out.
// Block: 64 rows x FULL 512 cols; 512 thr = 8 waves (2 m x 4 n), acc[2][8].
// LDS: As 2x8KB + Bs 2x64KB = 144KB (1 block/CU; latency hidden by pipeline).
// Row stats: shfl_xor butterfly over 16 c-lanes -> cross-wave via dead As.
// ---------------------------------------------------------------------------
__global__ __launch_bounds__(512) void out_ln(
    const short* __restrict__ A, const short* __restrict__ Bw,
    const float* __restrict__ bias, const float* __restrict__ g,
    const float* __restrict__ bt, float* __restrict__ out)
{
    __shared__ short As[2][64 * 64];
    __shared__ short Bs[2][512 * 64];
    const int t = threadIdx.x, lane = t & 63, wv = t >> 6;
    const int c = lane & 15, quad = lane >> 4;
    const int wr = wv >> 2, wc = wv & 3;          // 2 x 4 wave grid
    const int rsub = lane >> 3;
    const int csA = (lane & 7) ^ rsub;
    const int m0 = blockIdx.x * 64;

    float bv[8], gg[8], bb[8];
    #pragma unroll
    for (int nj = 0; nj < 8; ++nj) {
        int col = wc * 128 + nj * 16 + c;
        bv[nj] = bias[col]; gg[nj] = g[col]; bb[nj] = bt[col];
    }

    f32x4 acc[2][8];
    #pragma unroll
    for (int mi = 0; mi < 2; ++mi)
        #pragma unroll
        for (int nj = 0; nj < 8; ++nj)
            #pragma unroll
            for (int i = 0; i < 4; ++i) acc[mi][nj][i] = 0.0f;

    // prologue: stage step 0 into buf 0
    gload16(A + (size_t)(m0 + wv * 8 + rsub) * 512 + csA * 8, &As[0][wv * 512]);
    #pragma unroll
    for (int p = 0; p < 8; ++p) {
        int r = p * 64 + wv * 8 + rsub;
        gload16(Bw + (size_t)r * 512 + csA * 8, &Bs[0][(p * 8 + wv) * 512]);
    }

    #pragma unroll 2
    for (int step = 0; step < 8; ++step) {
        const int cur = step & 1;
        __syncthreads();                     // drains buf[cur] loads
        if (step < 7) {
            int k0n = (step + 1) * 64;
            gload16(A + (size_t)(m0 + wv * 8 + rsub) * 512 + k0n + csA * 8,
                    &As[cur ^ 1][wv * 512]);
            #pragma unroll
            for (int p = 0; p < 8; ++p) {
                int r = p * 64 + wv * 8 + rsub;
                gload16(Bw + (size_t)r * 512 + k0n + csA * 8,
                        &Bs[cur ^ 1][(p * 8 + wv) * 512]);
            }
        }
        bf16x8 af[2][2];
        #pragma unroll
        for (int mi = 0; mi < 2; ++mi) {
            int ar = wr * 32 + mi * 16 + c;
            af[mi][0] = *(const bf16x8*)&As[cur][ar * 64 + ((quad       ^ (ar & 7)) * 8)];
            af[mi][1] = *(const bf16x8*)&As[cur][ar * 64 + (((4 + quad) ^ (ar & 7)) * 8)];
        }
        __builtin_amdgcn_s_setprio(1);
        #pragma unroll
        for (int nj = 0; nj < 8; ++nj) {
            int br = wc * 128 + nj * 16 + c;
            bf16x8 b0 = *(const bf16x8*)&Bs[cur][br * 64 + ((quad       ^ (br & 7)) * 8)];
            bf16x8 b1 = *(const bf16x8*)&Bs[cur][br * 64 + (((4 + quad) ^ (br & 7)) * 8)];
            #pragma unroll
            for (int mi = 0; mi < 2; ++mi) {
                acc[mi][nj] = __builtin_amdgcn_mfma_f32_16x16x32_bf16(af[mi][0], b0, acc[mi][nj], 0, 0, 0);
                acc[mi][nj] = __builtin_amdgcn_mfma_f32_16x16x32_bf16(af[mi][1], b1, acc[mi][nj], 0, 0, 0);
            }
        }
        __builtin_amdgcn_s_setprio(0);
    }
    __syncthreads();                       // all frag reads done; As reusable

    float* red = (float*)&As[0][0];        // s: [4 wc][64 row], ss at +256
    #pragma unroll
    for (int mi = 0; mi < 2; ++mi)
        #pragma unroll
        for (int i = 0; i < 4; ++i) {
            float s = 0.0f, ss = 0.0f;
            #pragma unroll
            for (int nj = 0; nj < 8; ++nj) {
                float z = acc[mi][nj][i] + bv[nj];
                s += z; ss += z * z;
            }
            s  += __shfl_xor(s, 1);  s  += __shfl_xor(s, 2);
            s  += __shfl_xor(s, 4);  s  += __shfl_xor(s, 8);
            ss += __shfl_xor(ss, 1); ss += __shfl_xor(ss, 2);
            ss += __shfl_xor(ss, 4); ss += __shfl_xor(ss, 8);
            if (c == 0) {
                int row = wr * 32 + mi * 16 + quad * 4 + i;
                red[wc * 64 + row]       = s;
                red[256 + wc * 64 + row] = ss;
            }
        }
    __syncthreads();
    #pragma unroll
    for (int mi = 0; mi < 2; ++mi)
        #pragma unroll
        for (int i = 0; i < 4; ++i) {
            int row = wr * 32 + mi * 16 + quad * 4 + i;
            float S1 = red[row] + red[64 + row] + red[128 + row] + red[192 + row];
            float S2 = red[256 + row] + red[320 + row] + red[384 + row] + red[448 + row];
            float mu   = S1 * (1.0f / DIM);
            float var  = S2 * (1.0f / DIM) - mu * mu;
            float rstd = rsqrtf(var + 1e-5f);
            float* orow = out + (size_t)(m0 + row) * DIM + wc * 128 + c;
            #pragma unroll
            for (int nj = 0; nj < 8; ++nj) {
                float z = acc[mi][nj][i] + bv[nj];
                orow[nj * 16] = elu_f((z - mu) * rstd * gg[nj] + bb[nj]);
            }
        }
}

extern "C" void kernel_launch(void* const* d_in, const int* in_sizes, int n_in,
                              void* d_out, int out_size, void* d_ws, size_t ws_size,
                              hipStream_t stream)
{
    const float* x    = (const float*)d_in[0];
    const int*   mask = (const int*)d_in[1];
    const float* Wqkv = (const float*)d_in[2];
    const float* bqkv = (const float*)d_in[3];
    const float* Wout = (const float*)d_in[4];
    const float* bout = (const float*)d_in[5];
    const float* ln_g = (const float*)d_in[6];
    const float* ln_b = (const float*)d_in[7];
    float* out = (float*)d_out;

    short* xb   = (short*)d_ws;           // QSZ
    short* Wp   = xb + QSZ;               // 786432
    short* Wob  = Wp + 786432;            // 262144
    short* QKV  = Wob + 262144;           // 3*QSZ  (Q | K | Vt)
    short* ATTb = QKV + 3 * (size_t)QSZ;  // QSZ
    float* bp   = (float*)(ATTb + QSZ);   // 1536
    float* Zb   = bp + 1536;              // region kept for maskf placement
    float* maskf = Zb + (size_t)QSZ - 16384;

    prep<<<9286, 256, 0, stream>>>(x, Wqkv, bqkv, Wout, mask, xb, Wp, bp, Wob, maskf);
    qkv_mfma<<<dim3(128, 12), 256, 0, stream>>>(xb, Wp, bp, QKV);
    attn_mfma<<<1024, 512, 0, stream>>>(QKV, QKV + QSZ, QKV + 2 * (size_t)QSZ, maskf, ATTb);
    out_ln<<<256, 512, 0, stream>>>(ATTb, Wob, bout, ln_g, ln_b, out);
}